// Round 12
// baseline (806.136 us; speedup 1.0000x reference)
//
#include <hip/hip_runtime.h>
#include <hip/hip_fp16.h>

#define B 256
#define T 128
#define D 76
#define H 128
#define G 512   // 4H
#define H2 256  // 2H

typedef unsigned int uint32;
typedef unsigned short ushort16;
typedef _Float16 h2_t __attribute__((ext_vector_type(2)));

__device__ __forceinline__ float sigm(float x){ return 1.0f/(1.0f+__expf(-x)); }
__device__ __forceinline__ float fast_rcp(float x){ float r; asm volatile("v_rcp_f32 %0, %1" : "=v"(r) : "v"(x)); return r; }
__device__ __forceinline__ float fast_tanh(float x){ return 1.0f - 2.0f*fast_rcp(1.0f + __expf(2.0f*x)); }
__device__ __forceinline__ float bflo(uint32 u){ return __uint_as_float(u<<16); }
__device__ __forceinline__ float bfhi(uint32 u){ return __uint_as_float(u & 0xffff0000u); }
__device__ __forceinline__ ushort16 f2bf(float f){ uint32 u=__float_as_uint(f); return (ushort16)((u + 0x7fffu + ((u>>16)&1u))>>16); }
__device__ __forceinline__ uint32 pk_f16(float a, float b){
  return (uint32)__half_as_ushort(__float2half(a)) | ((uint32)__half_as_ushort(__float2half(b))<<16);
}
__device__ __forceinline__ uint32 pk_bf16(float a, float b){
  return (uint32)f2bf(a) | ((uint32)f2bf(b)<<16);
}
__device__ __forceinline__ float dot2(uint32 w, uint32 h, float acc){
  return __builtin_amdgcn_fdot2(__builtin_bit_cast(h2_t, w), __builtin_bit_cast(h2_t, h), acc, false);
}

// ---------- weight transposes (2 segs: Wzmu, Wzlv) ----------
struct PrepArgs {
  const float* src[2];
  float* dst[2];
  int R[2]; int C[2];
};
__global__ __launch_bounds__(256) void prep_k(PrepArgs a){
  int seg = blockIdx.x >> 5;
  const float* s=a.src[seg]; float* d=a.dst[seg];
  int R=a.R[seg], C=a.C[seg], tot=R*C;
  for (int i=(blockIdx.x&31)*256+threadIdx.x; i<tot; i+=32*256){
    int r=i/C, c=i-r*C;
    d[(size_t)c*R + r] = s[i];
  }
}

// ---------- pack [N][K] f32 row-major -> [K/2][N] f16-pair u32 (9 segs) ----------
struct Pack2Args { const float* src[9]; uint32* dst[9]; int N[9]; int K[9]; };
__global__ __launch_bounds__(256) void pack2_k(Pack2Args a){
  int seg = blockIdx.x >> 5;
  const float* s=a.src[seg]; uint32* d=a.dst[seg];
  int N=a.N[seg], K=a.K[seg], tot=N*(K>>1);
  for (int i=(blockIdx.x&31)*256+threadIdx.x; i<tot; i+=32*256){
    int k2=i/N, j=i-k2*N;
    float2 w = *(const float2*)(s + (size_t)j*K + 2*k2);
    d[(size_t)k2*N + j] = pk_f16(w.x, w.y);
  }
}

// ---------- pack Whh (enc+dec) f16 k-pairs: wpk[phase][d][k2][j] ----------
__global__ __launch_bounds__(256) void pack_whh_k(
  const float* __restrict__ eWhh, const float* __restrict__ dWhh,
  uint32* __restrict__ wpkE, uint32* __restrict__ wpkD)
{
  int idx = blockIdx.x*256 + threadIdx.x;      // 131072 total
  int phase = idx >> 16;
  int rem = idx & 65535;
  int d = rem >> 15;
  int k2 = (rem >> 9) & 63;
  int j = rem & 511;
  const float* Wsrc = phase ? dWhh : eWhh;
  float2 wa = *(const float2*)(Wsrc + ((size_t)(d*512 + j))*128 + 2*k2);
  (phase ? wpkD : wpkE)[rem] = pk_f16(wa.x, wa.y);
}

// ---------- xg = x @ Wih^T + b via f16 dot2, flat f16 [d][b][t][512]. shift=1 for decoder ----------
__global__ __launch_bounds__(256) void xg_k(
  const float* __restrict__ x, const uint32* __restrict__ wx, const float* __restrict__ bias,
  __half* __restrict__ xgh, int shift)
{
  int d = blockIdx.x >> 11;
  int blk = blockIdx.x & 2047;
  int b = blk >> 3, t0 = (blk & 7) * 16;
  int tid = threadIdx.x;
  __shared__ __align__(16) uint32 xs[16][40];   // 38 used, rows padded to 160B
  for (int i=tid;i<16*38;i+=256){
    int r=i/38, k2=i-r*38, ts=t0+r-shift;
    float2 xv = (ts>=0) ? *(const float2*)(x + ((size_t)b*T+ts)*D + 2*k2) : make_float2(0.f,0.f);
    xs[r][k2] = pk_f16(xv.x, xv.y);
  }
  __syncthreads();
  const uint32* W = wx + (size_t)d*38*512;
  float a0[16], a1[16];
  #pragma unroll
  for(int r=0;r<16;r++){a0[r]=0.f;a1[r]=0.f;}
  #pragma unroll
  for (int k8=0;k8<9;k8++){
    int k2=4*k8;
    uint32 w00=W[(size_t)(k2+0)*512+tid], w01=W[(size_t)(k2+0)*512+tid+256];
    uint32 w10=W[(size_t)(k2+1)*512+tid], w11=W[(size_t)(k2+1)*512+tid+256];
    uint32 w20=W[(size_t)(k2+2)*512+tid], w21=W[(size_t)(k2+2)*512+tid+256];
    uint32 w30=W[(size_t)(k2+3)*512+tid], w31=W[(size_t)(k2+3)*512+tid+256];
    #pragma unroll
    for(int r=0;r<16;r++){
      uint4 u = *(const uint4*)&xs[r][k2];
      a0[r]=dot2(u.x,w00,a0[r]); a0[r]=dot2(u.y,w10,a0[r]);
      a0[r]=dot2(u.z,w20,a0[r]); a0[r]=dot2(u.w,w30,a0[r]);
      a1[r]=dot2(u.x,w01,a1[r]); a1[r]=dot2(u.y,w11,a1[r]);
      a1[r]=dot2(u.z,w21,a1[r]); a1[r]=dot2(u.w,w31,a1[r]);
    }
  }
  { // tail: k2 = 36, 37
    uint32 w00=W[(size_t)36*512+tid], w01=W[(size_t)36*512+tid+256];
    uint32 w10=W[(size_t)37*512+tid], w11=W[(size_t)37*512+tid+256];
    #pragma unroll
    for(int r=0;r<16;r++){
      uint2 u = *(const uint2*)&xs[r][36];
      a0[r]=dot2(u.x,w00,a0[r]); a0[r]=dot2(u.y,w10,a0[r]);
      a1[r]=dot2(u.x,w01,a1[r]); a1[r]=dot2(u.y,w11,a1[r]);
    }
  }
  float bb0=bias[d*G+tid], bb1=bias[d*G+tid+256];
  #pragma unroll
  for(int r=0;r<16;r++){
    size_t row = (size_t)(d*B + b)*T + (t0+r);
    xgh[row*512 + tid]       = __float2half(a0[r]+bb0);
    xgh[row*512 + tid + 256] = __float2half(a1[r]+bb1);
  }
}

// ---------- recurrence: block=(dir,b) 512 thr; weights in 64 VGPRs; b128 h reads; xg prefetch ----------
template<int ENC>
__global__ __launch_bounds__(512,2) void rec_k(
  const __half* __restrict__ xgh, const uint32* __restrict__ wpk,
  const __half* __restrict__ h16r, __half* __restrict__ on16,
  float* __restrict__ h_fin, uint32* __restrict__ h16w)
{
  int d = blockIdx.x >> 8;
  int b = blockIdx.x & 255;
  int tid = threadIdx.x;               // gate j in [0,512)
  __shared__ float gl[G];
  __shared__ __align__(16) __half hs_h[H];
  uint32 wreg[64];
  const uint32* wp = wpk + (size_t)d*64*512;
  #pragma unroll
  for (int k2=0;k2<64;k2++) wreg[k2] = wp[k2*512 + tid];
  if (tid < H){
    if (ENC) hs_h[tid] = __float2half(0.f);
    else     hs_h[tid] = h16r[((size_t)d*B + b)*H + tid];   // h16[t=0]
  }
  float creg = 0.f, hlast = 0.f;
  const __half* xrow = xgh + (size_t)(d*B + b)*T*512;
  int te0 = ENC ? (d ? (T-1) : 0) : 0;
  __half xr_next = xrow[(size_t)te0*512 + tid];
  __syncthreads();
  for (int t=0;t<T;t++){
    int te = ENC ? (d ? (T-1-t) : t) : t;
    __half xr = xr_next;
    if (t+1 < T){
      int tn = ENC ? (d ? (T-2-t) : (t+1)) : (t+1);
      xr_next = xrow[(size_t)tn*512 + tid];
    }
    const uint4* h128 = (const uint4*)hs_h;
    float acc0 = 0.f, acc1 = 0.f;
    #pragma unroll
    for (int k8=0;k8<16;k8++){
      uint4 hv4 = h128[k8];
      acc0 = dot2(wreg[4*k8+0], hv4.x, acc0);
      acc1 = dot2(wreg[4*k8+1], hv4.y, acc1);
      acc0 = dot2(wreg[4*k8+2], hv4.z, acc0);
      acc1 = dot2(wreg[4*k8+3], hv4.w, acc1);
    }
    gl[tid] = acc0 + acc1 + __half2float(xr);
    __syncthreads();
    if (tid < H){
      float ii=sigm(gl[tid]), ff=sigm(gl[128+tid]);
      float gg=fast_tanh(gl[256+tid]), oo=sigm(gl[384+tid]);
      creg = ff*creg + ii*gg;
      float hv = oo*fast_tanh(creg);
      hlast = hv;
      hs_h[tid] = __float2half(hv);
      if (ENC){
        on16[((size_t)b*T + te)*H2 + d*H + tid] = __float2half(hv);
      } else {
        float nb = __shfl_xor(hv, 1);
        if ((tid&1)==0)
          h16w[(((size_t)(t+1)*2 + d)*B + b)*64 + (tid>>1)] = pk_f16(hv, nb);
      }
    }
    __syncthreads();
  }
  if (ENC && tid < H) h_fin[(size_t)d*B*H + (size_t)b*H + tid] = hlast;
}

// ---------- z = mu + eps*exp(0.5 lv) -> h16[0] (f16 pairs) ----------
__global__ __launch_bounds__(128) void z_k(
  const float* __restrict__ h_fin, const float* __restrict__ WzmuT, const float* __restrict__ bzmu,
  const float* __restrict__ WzlvT, const float* __restrict__ bzlv, const float* __restrict__ eps_z,
  uint32* __restrict__ h16w)
{
  __shared__ float hr[H];
  int d = blockIdx.x >> 8; int b = blockIdx.x & 255;
  int j = threadIdx.x;
  hr[j] = h_fin[(size_t)d*B*H + (size_t)b*H + j];
  __syncthreads();
  float mu=bzmu[j], lv=bzlv[j];
  #pragma unroll 4
  for(int k=0;k<H;k++){ float hv=hr[k]; mu+=hv*WzmuT[k*H+j]; lv+=hv*WzlvT[k*H+j]; }
  float z = mu + eps_z[(size_t)d*B*H + (size_t)b*H + j]*__expf(0.5f*lv);
  float nb = __shfl_xor(z, 1);
  if ((j&1)==0)
    h16w[(((size_t)0*2 + d)*B + b)*64 + (j>>1)] = pk_f16(z, nb);
}

// ---------- fused on_s (f16 dot2 GEMMs, b128 LDS): onsT + eb ----------
__global__ __launch_bounds__(256) void onsw2v_k(
  const uint32* __restrict__ on32, const uint32* __restrict__ wpmu, const float* __restrict__ bomu,
  const uint32* __restrict__ wplv, const float* __restrict__ bolv, const float* __restrict__ eps_on,
  const uint32* __restrict__ wp2, const float* __restrict__ b2,
  uint32* __restrict__ onsT, float* __restrict__ ebg)
{
  __shared__ __align__(16) uint32 tl[16][128];     // on (f16 pairs along k)
  __shared__ __align__(16) uint32 t2p[16][128];    // on_s (f16 pairs along j)
  size_t row0=(size_t)blockIdx.x*16;
  int b = (int)(row0 >> 7), t0 = (int)(row0 & 127);
  int tid=threadIdx.x;
  for(int i=tid;i<16*128;i+=256) ((uint32*)tl)[i] = on32[row0*128 + i];
  __syncthreads();
  float am[16], al[16];
  #pragma unroll
  for(int r=0;r<16;r++){am[r]=0.f;al[r]=0.f;}
  for(int k8=0;k8<32;k8++){
    int k2=4*k8;
    uint32 wm0=wpmu[(size_t)(k2+0)*H2+tid], wm1=wpmu[(size_t)(k2+1)*H2+tid];
    uint32 wm2=wpmu[(size_t)(k2+2)*H2+tid], wm3=wpmu[(size_t)(k2+3)*H2+tid];
    uint32 wl0=wplv[(size_t)(k2+0)*H2+tid], wl1=wplv[(size_t)(k2+1)*H2+tid];
    uint32 wl2=wplv[(size_t)(k2+2)*H2+tid], wl3=wplv[(size_t)(k2+3)*H2+tid];
    #pragma unroll
    for(int r=0;r<16;r++){
      uint4 u = *(const uint4*)&tl[r][k2];
      am[r]=dot2(u.x,wm0,am[r]); am[r]=dot2(u.y,wm1,am[r]);
      am[r]=dot2(u.z,wm2,am[r]); am[r]=dot2(u.w,wm3,am[r]);
      al[r]=dot2(u.x,wl0,al[r]); al[r]=dot2(u.y,wl1,al[r]);
      al[r]=dot2(u.z,wl2,al[r]); al[r]=dot2(u.w,wl3,al[r]);
    }
  }
  float bm=bomu[tid], bl=bolv[tid];
  float vv[16];
  #pragma unroll
  for(int r=0;r<16;r++){
    size_t row=row0+r;
    vv[r] = am[r]+bm + eps_on[row*H2+tid]*__expf(0.5f*(al[r]+bl));
  }
  // pack on_s pairs along j via shfl (even lanes write)
  #pragma unroll
  for(int r=0;r<16;r++){
    float nb = __shfl_xor(vv[r], 1);
    if ((tid&1)==0) t2p[r][tid>>1] = pk_f16(vv[r], nb);
  }
  __syncthreads();
  // on_s^T f16 t-pairs for PV: onsT[(b*256 + j)*64 + t/2]
  #pragma unroll
  for(int rr=0;rr<8;rr++){
    uint32 ua = t2p[2*rr][tid>>1], ub = t2p[2*rr+1][tid>>1];
    uint32 ha = (tid&1) ? (ua>>16) : (ua & 0xffffu);
    uint32 hb = (tid&1) ? (ub>>16) : (ub & 0xffffu);
    onsT[((size_t)b*H2 + tid)*64 + (t0>>1) + rr] = ha | (hb<<16);
  }
  // eb = exp(2*(on_s @ W2^T + b2))
  float ac[16];
  #pragma unroll
  for(int r=0;r<16;r++) ac[r]=0.f;
  for(int k8=0;k8<32;k8++){
    int k2=4*k8;
    uint32 w0=wp2[(size_t)(k2+0)*H2+tid], w1=wp2[(size_t)(k2+1)*H2+tid];
    uint32 w2=wp2[(size_t)(k2+2)*H2+tid], w3=wp2[(size_t)(k2+3)*H2+tid];
    #pragma unroll
    for(int r=0;r<16;r++){
      uint4 u = *(const uint4*)&t2p[r][k2];
      ac[r]=dot2(u.x,w0,ac[r]); ac[r]=dot2(u.y,w1,ac[r]);
      ac[r]=dot2(u.z,w2,ac[r]); ac[r]=dot2(u.w,w3,ac[r]);
    }
  }
  float bb=b2[tid];
  #pragma unroll
  for(int r=0;r<16;r++) ebg[(row0+r)*H2+tid]=__expf(2.0f*(ac[r]+bb));
}

// ---------- eq = exp(2*(concat(h0,h1)@W1T+b1)) via f16 dot2, b128 LDS ----------
__global__ __launch_bounds__(256) void qp_all_k(
  const uint32* __restrict__ h16, const uint32* __restrict__ wp1, const float* __restrict__ b1,
  float* __restrict__ eqg)
{
  int m0 = blockIdx.x*16; int b = m0>>7; int t0 = m0&127;
  __shared__ __align__(16) uint32 tile[16][128];
  int tid=threadIdx.x;
  for (int i=tid;i<16*128;i+=256){
    int r=i>>7, c=i&127; int dd=c>>6, kk2=c&63;
    tile[r][c] = h16[(((size_t)(t0+r)*2 + dd)*B + b)*64 + kk2];
  }
  __syncthreads();
  float ac[16];
  #pragma unroll
  for(int r=0;r<16;r++) ac[r]=0.f;
  for(int k8=0;k8<32;k8++){
    int k2=4*k8;
    uint32 w0=wp1[(size_t)(k2+0)*H2+tid], w1=wp1[(size_t)(k2+1)*H2+tid];
    uint32 w2=wp1[(size_t)(k2+2)*H2+tid], w3=wp1[(size_t)(k2+3)*H2+tid];
    #pragma unroll
    for(int r=0;r<16;r++){
      uint4 u = *(const uint4*)&tile[r][k2];
      ac[r]=dot2(u.x,w0,ac[r]); ac[r]=dot2(u.y,w1,ac[r]);
      ac[r]=dot2(u.z,w2,ac[r]); ac[r]=dot2(u.w,w3,ac[r]);
    }
  }
  float bb=b1[tid];
  #pragma unroll
  for(int r=0;r<16;r++) eqg[(size_t)(m0+r)*H2+tid]=__expf(2.0f*(ac[r]+bb));
}

// ---------- scores: TQ=2; thread jq owns j=16jq..16jq+15 -> b128 eq/wv reads; (512,4) ----------
// VGPR plan: 32 ebp + 8 acc + eq/wv float4 working ~12 + addr ~8 = ~60 < 64 cap (52 measured in R11).
__global__ __launch_bounds__(512,4) void score_k(
  const float* __restrict__ eqg, const float* __restrict__ ebg,
  const float* __restrict__ att_v, uint32* __restrict__ sc16)
{
  int b  = blockIdx.x >> 1;
  int t0 = (blockIdx.x & 1) * 64;
  int tid = threadIdx.x;
  int jq = tid & 15, ttb = tid >> 4;
  __shared__ __align__(16) float eqs[2][2*H2];
  __shared__ __align__(16) float scl[2][2][T];
  __shared__ float wsum4[2][4];
  __shared__ __align__(16) float wvs[H2];
  uint32 ebp01[16], ebp23[16];
  float vsum_mine = 0.f;
  {
    const float* ebb = ebg + (size_t)b*T*H2;
    #pragma unroll
    for (int ii=0;ii<16;ii++){
      int j = 16*jq + ii;
      ebp01[ii] = pk_bf16(ebb[(size_t)(ttb    )*H2 + j], ebb[(size_t)(ttb+32)*H2 + j]);
      ebp23[ii] = pk_bf16(ebb[(size_t)(ttb+64 )*H2 + j], ebb[(size_t)(ttb+96)*H2 + j]);
      vsum_mine += att_v[j];
    }
  }
  if (tid < H2) wvs[tid] = -2.0f*att_v[tid];
  if (tid < 128) ((float4*)eqs[0])[tid] = ((const float4*)(eqg + ((size_t)b*T + t0)*H2))[tid];
  __syncthreads();
  int buf = 0;
  for (int tq=0; tq<64; tq+=2){
    int cur = (tq>>1)&1;
    if (tq+2 < 64 && tid < 128)
      ((float4*)eqs[buf^1])[tid] = ((const float4*)(eqg + ((size_t)b*T + t0+tq+2)*H2))[tid];
    const float* eq0 = eqs[buf];
    const float* eq1 = eqs[buf] + H2;
    float a00=vsum_mine,a01=vsum_mine,a02=vsum_mine,a03=vsum_mine;
    float a10=vsum_mine,a11=vsum_mine,a12=vsum_mine,a13=vsum_mine;
    #pragma unroll
    for (int ii4=0; ii4<4; ii4++){
      float4 q0 = *(const float4*)&eq0[16*jq + 4*ii4];
      float4 q1 = *(const float4*)&eq1[16*jq + 4*ii4];
      float4 w4 = *(const float4*)&wvs[16*jq + 4*ii4];
      #pragma unroll
      for (int c=0;c<4;c++){
        int ii = 4*ii4 + c;
        float e0=bflo(ebp01[ii]), e1=bfhi(ebp01[ii]);
        float e2=bflo(ebp23[ii]), e3=bfhi(ebp23[ii]);
        float q0c = (c==0)?q0.x:(c==1)?q0.y:(c==2)?q0.z:q0.w;
        float q1c = (c==0)?q1.x:(c==1)?q1.y:(c==2)?q1.z:q1.w;
        float w   = (c==0)?w4.x:(c==1)?w4.y:(c==2)?w4.z:w4.w;
        a00 = fmaf(w, fast_rcp(fmaf(e0,q0c,1.f)), a00);
        a01 = fmaf(w, fast_rcp(fmaf(e1,q0c,1.f)), a01);
        a02 = fmaf(w, fast_rcp(fmaf(e2,q0c,1.f)), a02);
        a03 = fmaf(w, fast_rcp(fmaf(e3,q0c,1.f)), a03);
        a10 = fmaf(w, fast_rcp(fmaf(e0,q1c,1.f)), a10);
        a11 = fmaf(w, fast_rcp(fmaf(e1,q1c,1.f)), a11);
        a12 = fmaf(w, fast_rcp(fmaf(e2,q1c,1.f)), a12);
        a13 = fmaf(w, fast_rcp(fmaf(e3,q1c,1.f)), a13);
      }
    }
    #pragma unroll
    for (int off=1; off<16; off<<=1){
      a00 += __shfl_xor(a00,off); a01 += __shfl_xor(a01,off);
      a02 += __shfl_xor(a02,off); a03 += __shfl_xor(a03,off);
      a10 += __shfl_xor(a10,off); a11 += __shfl_xor(a11,off);
      a12 += __shfl_xor(a12,off); a13 += __shfl_xor(a13,off);
    }
    if (jq==0){
      scl[cur][0][ttb]=__expf(a00); scl[cur][0][ttb+32]=__expf(a01);
      scl[cur][0][ttb+64]=__expf(a02); scl[cur][0][ttb+96]=__expf(a03);
      scl[cur][1][ttb]=__expf(a10); scl[cur][1][ttb+32]=__expf(a11);
      scl[cur][1][ttb+64]=__expf(a12); scl[cur][1][ttb+96]=__expf(a13);
    }
    __syncthreads();                          // A: scl[cur] ready
    if (tid < 256){
      int row = tid>>7;
      float e = scl[cur][row][tid&127];
      #pragma unroll
      for (int off=1; off<64; off<<=1) e += __shfl_xor(e,off);
      if ((tid&63)==0) wsum4[cur][tid>>6]=e;
    }
    __syncthreads();                          // B: wsum ready
    if (tid < 128){
      int row = tid>>6, i = tid&63;
      float tot = wsum4[cur][row*2] + wsum4[cur][row*2+1];
      float inv = fast_rcp(tot*128.0f);
      sc16[((size_t)b*T + t0+tq+row)*64 + i] =
        pk_f16(scl[cur][row][2*i]*inv, scl[cur][row][2*i+1]*inv);
    }
    buf ^= 1;
  }
}

// ---------- fused PV + output projection: ctx never leaves LDS ----------
__global__ __launch_bounds__(256,2) void pvout_k(
  const uint32* __restrict__ sc16, const uint32* __restrict__ onsT,
  const uint32* __restrict__ h16, const uint32* __restrict__ wpout,
  const float* __restrict__ bout, float* __restrict__ out)
{
  int b  = blockIdx.x >> 3;
  int t0 = (blockIdx.x & 7) * 16;
  int m0 = blockIdx.x*16;
  int tid = threadIdx.x;                 // PV: output column j
  __shared__ uint32 scs[16][64];                   // 4 KB
  __shared__ __align__(16) uint32 rb[16][256];     // 16 KB: [h0|h1|ctx] f16 pairs
  uint4 vreg[16];
  {
    const uint4* vp = (const uint4*)(onsT + ((size_t)b*H2 + tid)*64);
    #pragma unroll
    for (int k=0;k<16;k++) vreg[k] = vp[k];
  }
  for (int i=tid;i<1024;i+=256) ((uint32*)scs)[i] = sc16[((size_t)b*T + t0)*64 + i];
  // h-part of rb: rows r, cols 0..127
  for (int i=tid;i<16*128;i+=256){
    int r=i>>7, c=i&127;
    int t = t0+r;
    rb[r][c] = (c<64) ? h16[(((size_t)(t+1)*2 + 0)*B + b)*64 + c]
                      : h16[(((size_t)(t+1)*2 + 1)*B + b)*64 + (c-64)];
  }
  __syncthreads();
  // phase A: PV -> ctx into rb[.][128..255]
  for (int qt=0; qt<16; qt++){
    float a0=0.f,a1=0.f,a2=0.f,a3=0.f;
    #pragma unroll
    for (int k=0;k<16;k++){
      a0 = dot2(scs[qt][4*k+0], vreg[k].x, a0);
      a1 = dot2(scs[qt][4*k+1], vreg[k].y, a1);
      a2 = dot2(scs[qt][4*k+2], vreg[k].z, a2);
      a3 = dot2(scs[qt][4*k+3], vreg[k].w, a3);
    }
    float mine = (a0+a1)+(a2+a3);
    float nb = __shfl_xor(mine, 1);
    if ((tid&1)==0) rb[qt][128 + (tid>>1)] = pk_f16(mine, nb);
  }
  __syncthreads();
  // phase B: out = rb @ Wout^T + bout
  for (int o=tid;o<16*D;o+=256){
    int r=o/D, j=o-r*D;
    float acc=bout[j];
    for (int k4=0;k4<64;k4++){
      uint4 u = *(const uint4*)&rb[r][4*k4];
      acc = dot2(u.x, wpout[(size_t)(4*k4+0)*D+j], acc);
      acc = dot2(u.y, wpout[(size_t)(4*k4+1)*D+j], acc);
      acc = dot2(u.z, wpout[(size_t)(4*k4+2)*D+j], acc);
      acc = dot2(u.w, wpout[(size_t)(4*k4+3)*D+j], acc);
    }
    out[((size_t)(m0+r))*D + j]=acc;
  }
}

extern "C" void kernel_launch(void* const* d_in, const int* in_sizes, int n_in,
                              void* d_out, int out_size, void* d_ws, size_t ws_size,
                              hipStream_t stream) {
  const float* x      =(const float*)d_in[0];
  const float* eps_z  =(const float*)d_in[1];
  const float* eps_on =(const float*)d_in[2];
  const float* enc_Wih=(const float*)d_in[3];
  const float* enc_Whh=(const float*)d_in[4];
  const float* enc_b  =(const float*)d_in[5];
  const float* dec_Wih=(const float*)d_in[6];
  const float* dec_Whh=(const float*)d_in[7];
  const float* dec_b  =(const float*)d_in[8];
  const float* Wzmu=(const float*)d_in[9];  const float* bzmu=(const float*)d_in[10];
  const float* Wzlv=(const float*)d_in[11]; const float* bzlv=(const float*)d_in[12];
  const float* Womu=(const float*)d_in[13]; const float* bomu=(const float*)d_in[14];
  const float* Wolv=(const float*)d_in[15]; const float* bolv=(const float*)d_in[16];
  const float* att_v=(const float*)d_in[17];
  const float* att_W1=(const float*)d_in[18]; const float* att_b1=(const float*)d_in[19];
  const float* att_W2=(const float*)d_in[20]; const float* att_b2=(const float*)d_in[21];
  const float* Wout=(const float*)d_in[22];  const float* bout=(const float*)d_in[23];
  float* out=(float*)d_out;
  float* ws=(float*)d_ws;
  (void)ws_size; (void)n_in; (void)in_sizes; (void)out_size;

  size_t o=0;
  float* WzmuT=ws+o; o+=H*H;
  float* WzlvT=ws+o; o+=H*H;
  uint32* wpkE=(uint32*)(ws+o); o+=65536;
  uint32* wpkD=(uint32*)(ws+o); o+=65536;
  uint32* wpmu=(uint32*)(ws+o); o+=32768;   // [k2=128][256]
  uint32* wplv=(uint32*)(ws+o); o+=32768;
  uint32* wp1 =(uint32*)(ws+o); o+=32768;
  uint32* wp2 =(uint32*)(ws+o); o+=32768;
  uint32* wpout=(uint32*)(ws+o); o+=19456;  // [k2=256][76]
  uint32* wxE =(uint32*)(ws+o); o+=38912;   // [d][k2=38][512]
  uint32* wxD =(uint32*)(ws+o); o+=38912;
  float* h_fin=ws+o; o+=2*B*H;
  __half* on16=(__half*)(ws+o); o+=(size_t)B*T*H2/2;
  uint32* h16 =(uint32*)(ws+o); o+=(size_t)(T+1)*2*B*64;   // f16 pairs [t][d][b][h/2]
  float* Abase=ws+o; o+=16777216;                // 64MB: xgh -> eqg
  float* Cbase=ws+o; o+=14680064;                // 56MB: onsT 16MB + ebg 32MB + sc16 8MB

  __half* xgh = (__half*)Abase;
  float* eqg  = Abase;
  uint32* onsT = (uint32*)Cbase;
  float* ebg  = Cbase + 4194304;
  uint32* sc16 = (uint32*)(Cbase + 4194304 + 8388608);

  PrepArgs pa;
  {
    const float* srcs[2]={Wzmu,Wzlv};
    float* dsts[2]={WzmuT,WzlvT};
    for(int i=0;i<2;i++){pa.src[i]=srcs[i];pa.dst[i]=dsts[i];pa.R[i]=H;pa.C[i]=H;}
  }
  Pack2Args p2;
  {
    const float* srcs[9]={Womu,Wolv,att_W1,att_W2,Wout,
                          enc_Wih, enc_Wih + (size_t)512*76,
                          dec_Wih, dec_Wih + (size_t)512*76};
    uint32* dsts[9]={wpmu,wplv,wp1,wp2,wpout, wxE, wxE+19456, wxD, wxD+19456};
    int Ns[9]={H2,H2,H2,H2,D, 512,512,512,512};
    int Ks[9]={H2,H2,H2,H2,G, D,D,D,D};
    for(int i=0;i<9;i++){p2.src[i]=srcs[i];p2.dst[i]=dsts[i];p2.N[i]=Ns[i];p2.K[i]=Ks[i];}
  }
  prep_k<<<64,256,0,stream>>>(pa);
  pack2_k<<<288,256,0,stream>>>(p2);
  pack_whh_k<<<512,256,0,stream>>>(enc_Whh, dec_Whh, wpkE, wpkD);

  // encoder phase
  xg_k<<<4096,256,0,stream>>>(x, wxE, enc_b, xgh, 0);
  rec_k<1><<<512,512,0,stream>>>(xgh, wpkE, nullptr, on16, h_fin, nullptr);
  z_k<<<512,128,0,stream>>>(h_fin, WzmuT,bzmu,WzlvT,bzlv,eps_z, h16);
  onsw2v_k<<<2048,256,0,stream>>>((const uint32*)on16,wpmu,bomu,wplv,bolv,eps_on,wp2,att_b2,onsT,ebg);

  // decoder phase (xgh reuses region A; eqg overwrites it after rec_k<0>)
  xg_k<<<4096,256,0,stream>>>(x, wxD, dec_b, xgh, 1);
  rec_k<0><<<512,512,0,stream>>>(xgh, wpkD, (const __half*)h16, nullptr, nullptr, h16);

  qp_all_k<<<2048,256,0,stream>>>(h16, wp1, att_b1, eqg);
  score_k<<<512,512,0,stream>>>(eqg, ebg, att_v, sc16);
  pvout_k<<<2048,256,0,stream>>>(sc16, onsT, h16, wpout, bout, out);
}

// Round 13
// 802.694 us; speedup vs baseline: 1.0043x; 1.0043x over previous
//
#include <hip/hip_runtime.h>
#include <hip/hip_fp16.h>

#define B 256
#define T 128
#define D 76
#define H 128
#define G 512   // 4H
#define H2 256  // 2H

typedef unsigned int uint32;
typedef unsigned short ushort16;
typedef _Float16 h2_t __attribute__((ext_vector_type(2)));

__device__ __forceinline__ float sigm(float x){ return 1.0f/(1.0f+__expf(-x)); }
__device__ __forceinline__ float fast_rcp(float x){ float r; asm volatile("v_rcp_f32 %0, %1" : "=v"(r) : "v"(x)); return r; }
__device__ __forceinline__ float fast_tanh(float x){ return 1.0f - 2.0f*fast_rcp(1.0f + __expf(2.0f*x)); }
__device__ __forceinline__ float bflo(uint32 u){ return __uint_as_float(u<<16); }
__device__ __forceinline__ float bfhi(uint32 u){ return __uint_as_float(u & 0xffff0000u); }
__device__ __forceinline__ ushort16 f2bf(float f){ uint32 u=__float_as_uint(f); return (ushort16)((u + 0x7fffu + ((u>>16)&1u))>>16); }
__device__ __forceinline__ uint32 pk_f16(float a, float b){
  return (uint32)__half_as_ushort(__float2half(a)) | ((uint32)__half_as_ushort(__float2half(b))<<16);
}
__device__ __forceinline__ uint32 pk_bf16(float a, float b){
  return (uint32)f2bf(a) | ((uint32)f2bf(b)<<16);
}
__device__ __forceinline__ float dot2(uint32 w, uint32 h, float acc){
  return __builtin_amdgcn_fdot2(__builtin_bit_cast(h2_t, w), __builtin_bit_cast(h2_t, h), acc, false);
}

// ---------- weight transposes (2 segs: Wzmu, Wzlv) ----------
struct PrepArgs {
  const float* src[2];
  float* dst[2];
  int R[2]; int C[2];
};
__global__ __launch_bounds__(256) void prep_k(PrepArgs a){
  int seg = blockIdx.x >> 5;
  const float* s=a.src[seg]; float* d=a.dst[seg];
  int R=a.R[seg], C=a.C[seg], tot=R*C;
  for (int i=(blockIdx.x&31)*256+threadIdx.x; i<tot; i+=32*256){
    int r=i/C, c=i-r*C;
    d[(size_t)c*R + r] = s[i];
  }
}

// ---------- pack [N][K] f32 row-major -> [K/2][N] f16-pair u32 (9 segs) ----------
struct Pack2Args { const float* src[9]; uint32* dst[9]; int N[9]; int K[9]; };
__global__ __launch_bounds__(256) void pack2_k(Pack2Args a){
  int seg = blockIdx.x >> 5;
  const float* s=a.src[seg]; uint32* d=a.dst[seg];
  int N=a.N[seg], K=a.K[seg], tot=N*(K>>1);
  for (int i=(blockIdx.x&31)*256+threadIdx.x; i<tot; i+=32*256){
    int k2=i/N, j=i-k2*N;
    float2 w = *(const float2*)(s + (size_t)j*K + 2*k2);
    d[(size_t)k2*N + j] = pk_f16(w.x, w.y);
  }
}

// ---------- pack Whh (enc+dec) f16 k-pairs: wpk[phase][d][k2][j] ----------
__global__ __launch_bounds__(256) void pack_whh_k(
  const float* __restrict__ eWhh, const float* __restrict__ dWhh,
  uint32* __restrict__ wpkE, uint32* __restrict__ wpkD)
{
  int idx = blockIdx.x*256 + threadIdx.x;      // 131072 total
  int phase = idx >> 16;
  int rem = idx & 65535;
  int d = rem >> 15;
  int k2 = (rem >> 9) & 63;
  int j = rem & 511;
  const float* Wsrc = phase ? dWhh : eWhh;
  float2 wa = *(const float2*)(Wsrc + ((size_t)(d*512 + j))*128 + 2*k2);
  (phase ? wpkD : wpkE)[rem] = pk_f16(wa.x, wa.y);
}

// ---------- xg = x @ Wih^T + b via f16 dot2, flat f16 [d][b][t][512]. shift=1 for decoder ----------
__global__ __launch_bounds__(256) void xg_k(
  const float* __restrict__ x, const uint32* __restrict__ wx, const float* __restrict__ bias,
  __half* __restrict__ xgh, int shift)
{
  int d = blockIdx.x >> 11;
  int blk = blockIdx.x & 2047;
  int b = blk >> 3, t0 = (blk & 7) * 16;
  int tid = threadIdx.x;
  __shared__ __align__(16) uint32 xs[16][40];   // 38 used, rows padded to 160B
  for (int i=tid;i<16*38;i+=256){
    int r=i/38, k2=i-r*38, ts=t0+r-shift;
    float2 xv = (ts>=0) ? *(const float2*)(x + ((size_t)b*T+ts)*D + 2*k2) : make_float2(0.f,0.f);
    xs[r][k2] = pk_f16(xv.x, xv.y);
  }
  __syncthreads();
  const uint32* W = wx + (size_t)d*38*512;
  float a0[16], a1[16];
  #pragma unroll
  for(int r=0;r<16;r++){a0[r]=0.f;a1[r]=0.f;}
  #pragma unroll
  for (int k8=0;k8<9;k8++){
    int k2=4*k8;
    uint32 w00=W[(size_t)(k2+0)*512+tid], w01=W[(size_t)(k2+0)*512+tid+256];
    uint32 w10=W[(size_t)(k2+1)*512+tid], w11=W[(size_t)(k2+1)*512+tid+256];
    uint32 w20=W[(size_t)(k2+2)*512+tid], w21=W[(size_t)(k2+2)*512+tid+256];
    uint32 w30=W[(size_t)(k2+3)*512+tid], w31=W[(size_t)(k2+3)*512+tid+256];
    #pragma unroll
    for(int r=0;r<16;r++){
      uint4 u = *(const uint4*)&xs[r][k2];
      a0[r]=dot2(u.x,w00,a0[r]); a0[r]=dot2(u.y,w10,a0[r]);
      a0[r]=dot2(u.z,w20,a0[r]); a0[r]=dot2(u.w,w30,a0[r]);
      a1[r]=dot2(u.x,w01,a1[r]); a1[r]=dot2(u.y,w11,a1[r]);
      a1[r]=dot2(u.z,w21,a1[r]); a1[r]=dot2(u.w,w31,a1[r]);
    }
  }
  { // tail: k2 = 36, 37
    uint32 w00=W[(size_t)36*512+tid], w01=W[(size_t)36*512+tid+256];
    uint32 w10=W[(size_t)37*512+tid], w11=W[(size_t)37*512+tid+256];
    #pragma unroll
    for(int r=0;r<16;r++){
      uint2 u = *(const uint2*)&xs[r][36];
      a0[r]=dot2(u.x,w00,a0[r]); a0[r]=dot2(u.y,w10,a0[r]);
      a1[r]=dot2(u.x,w01,a1[r]); a1[r]=dot2(u.y,w11,a1[r]);
    }
  }
  float bb0=bias[d*G+tid], bb1=bias[d*G+tid+256];
  #pragma unroll
  for(int r=0;r<16;r++){
    size_t row = (size_t)(d*B + b)*T + (t0+r);
    xgh[row*512 + tid]       = __float2half(a0[r]+bb0);
    xgh[row*512 + tid + 256] = __float2half(a1[r]+bb1);
  }
}

// ---------- recurrence: block=(dir,b) 512 thr; weights in 64 VGPRs; b128 h reads; xg prefetch ----------
template<int ENC>
__global__ __launch_bounds__(512,2) void rec_k(
  const __half* __restrict__ xgh, const uint32* __restrict__ wpk,
  const __half* __restrict__ h16r, __half* __restrict__ on16,
  float* __restrict__ h_fin, uint32* __restrict__ h16w)
{
  int d = blockIdx.x >> 8;
  int b = blockIdx.x & 255;
  int tid = threadIdx.x;               // gate j in [0,512)
  __shared__ float gl[G];
  __shared__ __align__(16) __half hs_h[H];
  uint32 wreg[64];
  const uint32* wp = wpk + (size_t)d*64*512;
  #pragma unroll
  for (int k2=0;k2<64;k2++) wreg[k2] = wp[k2*512 + tid];
  if (tid < H){
    if (ENC) hs_h[tid] = __float2half(0.f);
    else     hs_h[tid] = h16r[((size_t)d*B + b)*H + tid];   // h16[t=0]
  }
  float creg = 0.f, hlast = 0.f;
  const __half* xrow = xgh + (size_t)(d*B + b)*T*512;
  int te0 = ENC ? (d ? (T-1) : 0) : 0;
  __half xr_next = xrow[(size_t)te0*512 + tid];
  __syncthreads();
  for (int t=0;t<T;t++){
    int te = ENC ? (d ? (T-1-t) : t) : t;
    __half xr = xr_next;
    if (t+1 < T){
      int tn = ENC ? (d ? (T-2-t) : (t+1)) : (t+1);
      xr_next = xrow[(size_t)tn*512 + tid];
    }
    const uint4* h128 = (const uint4*)hs_h;
    float acc0 = 0.f, acc1 = 0.f;
    #pragma unroll
    for (int k8=0;k8<16;k8++){
      uint4 hv4 = h128[k8];
      acc0 = dot2(wreg[4*k8+0], hv4.x, acc0);
      acc1 = dot2(wreg[4*k8+1], hv4.y, acc1);
      acc0 = dot2(wreg[4*k8+2], hv4.z, acc0);
      acc1 = dot2(wreg[4*k8+3], hv4.w, acc1);
    }
    gl[tid] = acc0 + acc1 + __half2float(xr);
    __syncthreads();
    if (tid < H){
      float ii=sigm(gl[tid]), ff=sigm(gl[128+tid]);
      float gg=fast_tanh(gl[256+tid]), oo=sigm(gl[384+tid]);
      creg = ff*creg + ii*gg;
      float hv = oo*fast_tanh(creg);
      hlast = hv;
      hs_h[tid] = __float2half(hv);
      if (ENC){
        on16[((size_t)b*T + te)*H2 + d*H + tid] = __float2half(hv);
      } else {
        float nb = __shfl_xor(hv, 1);
        if ((tid&1)==0)
          h16w[(((size_t)(t+1)*2 + d)*B + b)*64 + (tid>>1)] = pk_f16(hv, nb);
      }
    }
    __syncthreads();
  }
  if (ENC && tid < H) h_fin[(size_t)d*B*H + (size_t)b*H + tid] = hlast;
}

// ---------- z = mu + eps*exp(0.5 lv) -> h16[0] (f16 pairs) ----------
__global__ __launch_bounds__(128) void z_k(
  const float* __restrict__ h_fin, const float* __restrict__ WzmuT, const float* __restrict__ bzmu,
  const float* __restrict__ WzlvT, const float* __restrict__ bzlv, const float* __restrict__ eps_z,
  uint32* __restrict__ h16w)
{
  __shared__ float hr[H];
  int d = blockIdx.x >> 8; int b = blockIdx.x & 255;
  int j = threadIdx.x;
  hr[j] = h_fin[(size_t)d*B*H + (size_t)b*H + j];
  __syncthreads();
  float mu=bzmu[j], lv=bzlv[j];
  #pragma unroll 4
  for(int k=0;k<H;k++){ float hv=hr[k]; mu+=hv*WzmuT[k*H+j]; lv+=hv*WzlvT[k*H+j]; }
  float z = mu + eps_z[(size_t)d*B*H + (size_t)b*H + j]*__expf(0.5f*lv);
  float nb = __shfl_xor(z, 1);
  if ((j&1)==0)
    h16w[(((size_t)0*2 + d)*B + b)*64 + (j>>1)] = pk_f16(z, nb);
}

// ---------- fused on_s (f16 dot2 GEMMs, b128 LDS): onsT + eb ----------
__global__ __launch_bounds__(256) void onsw2v_k(
  const uint32* __restrict__ on32, const uint32* __restrict__ wpmu, const float* __restrict__ bomu,
  const uint32* __restrict__ wplv, const float* __restrict__ bolv, const float* __restrict__ eps_on,
  const uint32* __restrict__ wp2, const float* __restrict__ b2,
  uint32* __restrict__ onsT, float* __restrict__ ebg)
{
  __shared__ __align__(16) uint32 tl[16][128];     // on (f16 pairs along k)
  __shared__ __align__(16) uint32 t2p[16][128];    // on_s (f16 pairs along j)
  size_t row0=(size_t)blockIdx.x*16;
  int b = (int)(row0 >> 7), t0 = (int)(row0 & 127);
  int tid=threadIdx.x;
  for(int i=tid;i<16*128;i+=256) ((uint32*)tl)[i] = on32[row0*128 + i];
  __syncthreads();
  float am[16], al[16];
  #pragma unroll
  for(int r=0;r<16;r++){am[r]=0.f;al[r]=0.f;}
  for(int k8=0;k8<32;k8++){
    int k2=4*k8;
    uint32 wm0=wpmu[(size_t)(k2+0)*H2+tid], wm1=wpmu[(size_t)(k2+1)*H2+tid];
    uint32 wm2=wpmu[(size_t)(k2+2)*H2+tid], wm3=wpmu[(size_t)(k2+3)*H2+tid];
    uint32 wl0=wplv[(size_t)(k2+0)*H2+tid], wl1=wplv[(size_t)(k2+1)*H2+tid];
    uint32 wl2=wplv[(size_t)(k2+2)*H2+tid], wl3=wplv[(size_t)(k2+3)*H2+tid];
    #pragma unroll
    for(int r=0;r<16;r++){
      uint4 u = *(const uint4*)&tl[r][k2];
      am[r]=dot2(u.x,wm0,am[r]); am[r]=dot2(u.y,wm1,am[r]);
      am[r]=dot2(u.z,wm2,am[r]); am[r]=dot2(u.w,wm3,am[r]);
      al[r]=dot2(u.x,wl0,al[r]); al[r]=dot2(u.y,wl1,al[r]);
      al[r]=dot2(u.z,wl2,al[r]); al[r]=dot2(u.w,wl3,al[r]);
    }
  }
  float bm=bomu[tid], bl=bolv[tid];
  float vv[16];
  #pragma unroll
  for(int r=0;r<16;r++){
    size_t row=row0+r;
    vv[r] = am[r]+bm + eps_on[row*H2+tid]*__expf(0.5f*(al[r]+bl));
  }
  // pack on_s pairs along j via shfl (even lanes write)
  #pragma unroll
  for(int r=0;r<16;r++){
    float nb = __shfl_xor(vv[r], 1);
    if ((tid&1)==0) t2p[r][tid>>1] = pk_f16(vv[r], nb);
  }
  __syncthreads();
  // on_s^T f16 t-pairs for PV: onsT[(b*256 + j)*64 + t/2]
  #pragma unroll
  for(int rr=0;rr<8;rr++){
    uint32 ua = t2p[2*rr][tid>>1], ub = t2p[2*rr+1][tid>>1];
    uint32 ha = (tid&1) ? (ua>>16) : (ua & 0xffffu);
    uint32 hb = (tid&1) ? (ub>>16) : (ub & 0xffffu);
    onsT[((size_t)b*H2 + tid)*64 + (t0>>1) + rr] = ha | (hb<<16);
  }
  // eb = exp(2*(on_s @ W2^T + b2))
  float ac[16];
  #pragma unroll
  for(int r=0;r<16;r++) ac[r]=0.f;
  for(int k8=0;k8<32;k8++){
    int k2=4*k8;
    uint32 w0=wp2[(size_t)(k2+0)*H2+tid], w1=wp2[(size_t)(k2+1)*H2+tid];
    uint32 w2=wp2[(size_t)(k2+2)*H2+tid], w3=wp2[(size_t)(k2+3)*H2+tid];
    #pragma unroll
    for(int r=0;r<16;r++){
      uint4 u = *(const uint4*)&t2p[r][k2];
      ac[r]=dot2(u.x,w0,ac[r]); ac[r]=dot2(u.y,w1,ac[r]);
      ac[r]=dot2(u.z,w2,ac[r]); ac[r]=dot2(u.w,w3,ac[r]);
    }
  }
  float bb=b2[tid];
  #pragma unroll
  for(int r=0;r<16;r++) ebg[(row0+r)*H2+tid]=__expf(2.0f*(ac[r]+bb));
}

// ---------- eq = exp(2*(concat(h0,h1)@W1T+b1)) via f16 dot2, b128 LDS ----------
__global__ __launch_bounds__(256) void qp_all_k(
  const uint32* __restrict__ h16, const uint32* __restrict__ wp1, const float* __restrict__ b1,
  float* __restrict__ eqg)
{
  int m0 = blockIdx.x*16; int b = m0>>7; int t0 = m0&127;
  __shared__ __align__(16) uint32 tile[16][128];
  int tid=threadIdx.x;
  for (int i=tid;i<16*128;i+=256){
    int r=i>>7, c=i&127; int dd=c>>6, kk2=c&63;
    tile[r][c] = h16[(((size_t)(t0+r)*2 + dd)*B + b)*64 + kk2];
  }
  __syncthreads();
  float ac[16];
  #pragma unroll
  for(int r=0;r<16;r++) ac[r]=0.f;
  for(int k8=0;k8<32;k8++){
    int k2=4*k8;
    uint32 w0=wp1[(size_t)(k2+0)*H2+tid], w1=wp1[(size_t)(k2+1)*H2+tid];
    uint32 w2=wp1[(size_t)(k2+2)*H2+tid], w3=wp1[(size_t)(k2+3)*H2+tid];
    #pragma unroll
    for(int r=0;r<16;r++){
      uint4 u = *(const uint4*)&tile[r][k2];
      ac[r]=dot2(u.x,w0,ac[r]); ac[r]=dot2(u.y,w1,ac[r]);
      ac[r]=dot2(u.z,w2,ac[r]); ac[r]=dot2(u.w,w3,ac[r]);
    }
  }
  float bb=b1[tid];
  #pragma unroll
  for(int r=0;r<16;r++) eqg[(size_t)(m0+r)*H2+tid]=__expf(2.0f*(ac[r]+bb));
}

// ---------- scores: grid (b, t-quarter of 32); TQ=2; padded 20-dword jq-blocks (bank-clean b128) ----------
// eqs/wvs layout: j = 16*jq + ii stored at dword jq*20 + ii (stride 20 -> banks spread, 2-way max).
__global__ __launch_bounds__(512,4) void score_k(
  const float* __restrict__ eqg, const float* __restrict__ ebg,
  const float* __restrict__ att_v, uint32* __restrict__ sc16)
{
  int b  = blockIdx.x >> 2;
  int t0 = (blockIdx.x & 3) * 32;
  int tid = threadIdx.x;
  int jq = tid & 15, ttb = tid >> 4;
  __shared__ __align__(16) float eqs[2][2*320];   // [buf][q*320 + jq*20 + ii]
  __shared__ __align__(16) float scl[2][2][T];
  __shared__ float wsum4[2][4];
  __shared__ __align__(16) float wvsp[320];       // padded -2*att_v
  uint32 ebp01[16], ebp23[16];
  float vsum_mine = 0.f;
  {
    const float* ebb = ebg + (size_t)b*T*H2;
    #pragma unroll
    for (int ii=0;ii<16;ii++){
      int j = 16*jq + ii;
      ebp01[ii] = pk_bf16(ebb[(size_t)(ttb    )*H2 + j], ebb[(size_t)(ttb+32)*H2 + j]);
      ebp23[ii] = pk_bf16(ebb[(size_t)(ttb+64 )*H2 + j], ebb[(size_t)(ttb+96)*H2 + j]);
      vsum_mine += att_v[j];
    }
  }
  if (tid < H2) wvsp[(tid>>4)*20 + (tid&15)] = -2.0f*att_v[tid];
  if (tid < 128){
    float4 v = ((const float4*)(eqg + ((size_t)b*T + t0)*H2))[tid];
    int l=4*tid, q=l>>8, jj=l&255;
    *(float4*)&eqs[0][q*320 + (jj>>4)*20 + (jj&15)] = v;
  }
  __syncthreads();
  int buf = 0;
  for (int tq=0; tq<32; tq+=2){
    int cur = (tq>>1)&1;
    if (tq+2 < 32 && tid < 128){
      float4 v = ((const float4*)(eqg + ((size_t)b*T + t0+tq+2)*H2))[tid];
      int l=4*tid, q=l>>8, jj=l&255;
      *(float4*)&eqs[buf^1][q*320 + (jj>>4)*20 + (jj&15)] = v;
    }
    const float* eq0 = eqs[buf];
    const float* eq1 = eqs[buf] + 320;
    float a00=vsum_mine,a01=vsum_mine,a02=vsum_mine,a03=vsum_mine;
    float a10=vsum_mine,a11=vsum_mine,a12=vsum_mine,a13=vsum_mine;
    #pragma unroll
    for (int ii4=0; ii4<4; ii4++){
      float4 q0 = *(const float4*)&eq0[jq*20 + 4*ii4];
      float4 q1 = *(const float4*)&eq1[jq*20 + 4*ii4];
      float4 w4 = *(const float4*)&wvsp[jq*20 + 4*ii4];
      #pragma unroll
      for (int c=0;c<4;c++){
        int ii = 4*ii4 + c;
        float e0=bflo(ebp01[ii]), e1=bfhi(ebp01[ii]);
        float e2=bflo(ebp23[ii]), e3=bfhi(ebp23[ii]);
        float q0c = (c==0)?q0.x:(c==1)?q0.y:(c==2)?q0.z:q0.w;
        float q1c = (c==0)?q1.x:(c==1)?q1.y:(c==2)?q1.z:q1.w;
        float w   = (c==0)?w4.x:(c==1)?w4.y:(c==2)?w4.z:w4.w;
        a00 = fmaf(w, fast_rcp(fmaf(e0,q0c,1.f)), a00);
        a01 = fmaf(w, fast_rcp(fmaf(e1,q0c,1.f)), a01);
        a02 = fmaf(w, fast_rcp(fmaf(e2,q0c,1.f)), a02);
        a03 = fmaf(w, fast_rcp(fmaf(e3,q0c,1.f)), a03);
        a10 = fmaf(w, fast_rcp(fmaf(e0,q1c,1.f)), a10);
        a11 = fmaf(w, fast_rcp(fmaf(e1,q1c,1.f)), a11);
        a12 = fmaf(w, fast_rcp(fmaf(e2,q1c,1.f)), a12);
        a13 = fmaf(w, fast_rcp(fmaf(e3,q1c,1.f)), a13);
      }
    }
    #pragma unroll
    for (int off=1; off<16; off<<=1){
      a00 += __shfl_xor(a00,off); a01 += __shfl_xor(a01,off);
      a02 += __shfl_xor(a02,off); a03 += __shfl_xor(a03,off);
      a10 += __shfl_xor(a10,off); a11 += __shfl_xor(a11,off);
      a12 += __shfl_xor(a12,off); a13 += __shfl_xor(a13,off);
    }
    if (jq==0){
      scl[cur][0][ttb]=__expf(a00); scl[cur][0][ttb+32]=__expf(a01);
      scl[cur][0][ttb+64]=__expf(a02); scl[cur][0][ttb+96]=__expf(a03);
      scl[cur][1][ttb]=__expf(a10); scl[cur][1][ttb+32]=__expf(a11);
      scl[cur][1][ttb+64]=__expf(a12); scl[cur][1][ttb+96]=__expf(a13);
    }
    __syncthreads();                          // A: scl[cur] ready
    if (tid < 256){
      int row = tid>>7;
      float e = scl[cur][row][tid&127];
      #pragma unroll
      for (int off=1; off<64; off<<=1) e += __shfl_xor(e,off);
      if ((tid&63)==0) wsum4[cur][tid>>6]=e;
    }
    __syncthreads();                          // B: wsum ready
    if (tid < 128){
      int row = tid>>6, i = tid&63;
      float tot = wsum4[cur][row*2] + wsum4[cur][row*2+1];
      float inv = fast_rcp(tot*128.0f);
      sc16[((size_t)b*T + t0+tq+row)*64 + i] =
        pk_f16(scl[cur][row][2*i]*inv, scl[cur][row][2*i+1]*inv);
    }
    buf ^= 1;
  }
}

// ---------- fused PV + output projection: ctx never leaves LDS ----------
__global__ __launch_bounds__(256,2) void pvout_k(
  const uint32* __restrict__ sc16, const uint32* __restrict__ onsT,
  const uint32* __restrict__ h16, const uint32* __restrict__ wpout,
  const float* __restrict__ bout, float* __restrict__ out)
{
  int b  = blockIdx.x >> 3;
  int t0 = (blockIdx.x & 7) * 16;
  int m0 = blockIdx.x*16;
  int tid = threadIdx.x;                 // PV: output column j
  __shared__ uint32 scs[16][64];                   // 4 KB
  __shared__ __align__(16) uint32 rb[16][256];     // 16 KB: [h0|h1|ctx] f16 pairs
  uint4 vreg[16];
  {
    const uint4* vp = (const uint4*)(onsT + ((size_t)b*H2 + tid)*64);
    #pragma unroll
    for (int k=0;k<16;k++) vreg[k] = vp[k];
  }
  for (int i=tid;i<1024;i+=256) ((uint32*)scs)[i] = sc16[((size_t)b*T + t0)*64 + i];
  // h-part of rb: rows r, cols 0..127
  for (int i=tid;i<16*128;i+=256){
    int r=i>>7, c=i&127;
    int t = t0+r;
    rb[r][c] = (c<64) ? h16[(((size_t)(t+1)*2 + 0)*B + b)*64 + c]
                      : h16[(((size_t)(t+1)*2 + 1)*B + b)*64 + (c-64)];
  }
  __syncthreads();
  // phase A: PV -> ctx into rb[.][128..255]
  for (int qt=0; qt<16; qt++){
    float a0=0.f,a1=0.f,a2=0.f,a3=0.f;
    #pragma unroll
    for (int k=0;k<16;k++){
      a0 = dot2(scs[qt][4*k+0], vreg[k].x, a0);
      a1 = dot2(scs[qt][4*k+1], vreg[k].y, a1);
      a2 = dot2(scs[qt][4*k+2], vreg[k].z, a2);
      a3 = dot2(scs[qt][4*k+3], vreg[k].w, a3);
    }
    float mine = (a0+a1)+(a2+a3);
    float nb = __shfl_xor(mine, 1);
    if ((tid&1)==0) rb[qt][128 + (tid>>1)] = pk_f16(mine, nb);
  }
  __syncthreads();
  // phase B: out = rb @ Wout^T + bout
  for (int o=tid;o<16*D;o+=256){
    int r=o/D, j=o-r*D;
    float acc=bout[j];
    for (int k4=0;k4<64;k4++){
      uint4 u = *(const uint4*)&rb[r][4*k4];
      acc = dot2(u.x, wpout[(size_t)(4*k4+0)*D+j], acc);
      acc = dot2(u.y, wpout[(size_t)(4*k4+1)*D+j], acc);
      acc = dot2(u.z, wpout[(size_t)(4*k4+2)*D+j], acc);
      acc = dot2(u.w, wpout[(size_t)(4*k4+3)*D+j], acc);
    }
    out[((size_t)(m0+r))*D + j]=acc;
  }
}

extern "C" void kernel_launch(void* const* d_in, const int* in_sizes, int n_in,
                              void* d_out, int out_size, void* d_ws, size_t ws_size,
                              hipStream_t stream) {
  const float* x      =(const float*)d_in[0];
  const float* eps_z  =(const float*)d_in[1];
  const float* eps_on =(const float*)d_in[2];
  const float* enc_Wih=(const float*)d_in[3];
  const float* enc_Whh=(const float*)d_in[4];
  const float* enc_b  =(const float*)d_in[5];
  const float* dec_Wih=(const float*)d_in[6];
  const float* dec_Whh=(const float*)d_in[7];
  const float* dec_b  =(const float*)d_in[8];
  const float* Wzmu=(const float*)d_in[9];  const float* bzmu=(const float*)d_in[10];
  const float* Wzlv=(const float*)d_in[11]; const float* bzlv=(const float*)d_in[12];
  const float* Womu=(const float*)d_in[13]; const float* bomu=(const float*)d_in[14];
  const float* Wolv=(const float*)d_in[15]; const float* bolv=(const float*)d_in[16];
  const float* att_v=(const float*)d_in[17];
  const float* att_W1=(const float*)d_in[18]; const float* att_b1=(const float*)d_in[19];
  const float* att_W2=(const float*)d_in[20]; const float* att_b2=(const float*)d_in[21];
  const float* Wout=(const float*)d_in[22];  const float* bout=(const float*)d_in[23];
  float* out=(float*)d_out;
  float* ws=(float*)d_ws;
  (void)ws_size; (void)n_in; (void)in_sizes; (void)out_size;

  size_t o=0;
  float* WzmuT=ws+o; o+=H*H;
  float* WzlvT=ws+o; o+=H*H;
  uint32* wpkE=(uint32*)(ws+o); o+=65536;
  uint32* wpkD=(uint32*)(ws+o); o+=65536;
  uint32* wpmu=(uint32*)(ws+o); o+=32768;   // [k2=128][256]
  uint32* wplv=(uint32*)(ws+o); o+=32768;
  uint32* wp1 =(uint32*)(ws+o); o+=32768;
  uint32* wp2 =(uint32*)(ws+o); o+=32768;
  uint32* wpout=(uint32*)(ws+o); o+=19456;  // [k2=256][76]
  uint32* wxE =(uint32*)(ws+o); o+=38912;   // [d][k2=38][512]
  uint32* wxD =(uint32*)(ws+o); o+=38912;
  float* h_fin=ws+o; o+=2*B*H;
  __half* on16=(__half*)(ws+o); o+=(size_t)B*T*H2/2;
  uint32* h16 =(uint32*)(ws+o); o+=(size_t)(T+1)*2*B*64;   // f16 pairs [t][d][b][h/2]
  float* Abase=ws+o; o+=16777216;                // 64MB: xgh -> eqg
  float* Cbase=ws+o; o+=14680064;                // 56MB: onsT 16MB + ebg 32MB + sc16 8MB

  __half* xgh = (__half*)Abase;
  float* eqg  = Abase;
  uint32* onsT = (uint32*)Cbase;
  float* ebg  = Cbase + 4194304;
  uint32* sc16 = (uint32*)(Cbase + 4194304 + 8388608);

  PrepArgs pa;
  {
    const float* srcs[2]={Wzmu,Wzlv};
    float* dsts[2]={WzmuT,WzlvT};
    for(int i=0;i<2;i++){pa.src[i]=srcs[i];pa.dst[i]=dsts[i];pa.R[i]=H;pa.C[i]=H;}
  }
  Pack2Args p2;
  {
    const float* srcs[9]={Womu,Wolv,att_W1,att_W2,Wout,
                          enc_Wih, enc_Wih + (size_t)512*76,
                          dec_Wih, dec_Wih + (size_t)512*76};
    uint32* dsts[9]={wpmu,wplv,wp1,wp2,wpout, wxE, wxE+19456, wxD, wxD+19456};
    int Ns[9]={H2,H2,H2,H2,D, 512,512,512,512};
    int Ks[9]={H2,H2,H2,H2,G, D,D,D,D};
    for(int i=0;i<9;i++){p2.src[i]=srcs[i];p2.dst[i]=dsts[i];p2.N[i]=Ns[i];p2.K[i]=Ks[i];}
  }
  prep_k<<<64,256,0,stream>>>(pa);
  pack2_k<<<288,256,0,stream>>>(p2);
  pack_whh_k<<<512,256,0,stream>>>(enc_Whh, dec_Whh, wpkE, wpkD);

  // encoder phase
  xg_k<<<4096,256,0,stream>>>(x, wxE, enc_b, xgh, 0);
  rec_k<1><<<512,512,0,stream>>>(xgh, wpkE, nullptr, on16, h_fin, nullptr);
  z_k<<<512,128,0,stream>>>(h_fin, WzmuT,bzmu,WzlvT,bzlv,eps_z, h16);
  onsw2v_k<<<2048,256,0,stream>>>((const uint32*)on16,wpmu,bomu,wplv,bolv,eps_on,wp2,att_b2,onsT,ebg);

  // decoder phase (xgh reuses region A; eqg overwrites it after rec_k<0>)
  xg_k<<<4096,256,0,stream>>>(x, wxD, dec_b, xgh, 1);
  rec_k<0><<<512,512,0,stream>>>(xgh, wpkD, (const __half*)h16, nullptr, nullptr, h16);

  qp_all_k<<<2048,256,0,stream>>>(h16, wp1, att_b1, eqg);
  score_k<<<1024,512,0,stream>>>(eqg, ebg, att_v, sc16);
  pvout_k<<<2048,256,0,stream>>>(sc16, onsT, h16, wpout, bout, out);
}

// Round 15
// 797.782 us; speedup vs baseline: 1.0105x; 1.0062x over previous
//
#include <hip/hip_runtime.h>
#include <hip/hip_fp16.h>

#define B 256
#define T 128
#define D 76
#define H 128
#define G 512   // 4H
#define H2 256  // 2H

typedef unsigned int uint32;
typedef unsigned short ushort16;
typedef _Float16 h2_t __attribute__((ext_vector_type(2)));

__device__ __forceinline__ float sigm(float x){ return 1.0f/(1.0f+__expf(-x)); }
__device__ __forceinline__ float fast_rcp(float x){ float r; asm volatile("v_rcp_f32 %0, %1" : "=v"(r) : "v"(x)); return r; }
__device__ __forceinline__ float fast_tanh(float x){ return 1.0f - 2.0f*fast_rcp(1.0f + __expf(2.0f*x)); }
__device__ __forceinline__ float bflo(uint32 u){ return __uint_as_float(u<<16); }
__device__ __forceinline__ float bfhi(uint32 u){ return __uint_as_float(u & 0xffff0000u); }
__device__ __forceinline__ ushort16 f2bf(float f){ uint32 u=__float_as_uint(f); return (ushort16)((u + 0x7fffu + ((u>>16)&1u))>>16); }
__device__ __forceinline__ uint32 pk_f16(float a, float b){
  return (uint32)__half_as_ushort(__float2half(a)) | ((uint32)__half_as_ushort(__float2half(b))<<16);
}
__device__ __forceinline__ uint32 pk_bf16(float a, float b){
  return (uint32)f2bf(a) | ((uint32)f2bf(b)<<16);
}
__device__ __forceinline__ float dot2(uint32 w, uint32 h, float acc){
  return __builtin_amdgcn_fdot2(__builtin_bit_cast(h2_t, w), __builtin_bit_cast(h2_t, h), acc, false);
}

// ---------- weight transposes (2 segs: Wzmu, Wzlv) ----------
struct PrepArgs {
  const float* src[2];
  float* dst[2];
  int R[2]; int C[2];
};
__global__ __launch_bounds__(256) void prep_k(PrepArgs a){
  int seg = blockIdx.x >> 5;
  const float* s=a.src[seg]; float* d=a.dst[seg];
  int R=a.R[seg], C=a.C[seg], tot=R*C;
  for (int i=(blockIdx.x&31)*256+threadIdx.x; i<tot; i+=32*256){
    int r=i/C, c=i-r*C;
    d[(size_t)c*R + r] = s[i];
  }
}

// ---------- pack [N][K] f32 row-major -> [K/2][N] f16-pair u32 (9 segs) ----------
struct Pack2Args { const float* src[9]; uint32* dst[9]; int N[9]; int K[9]; };
__global__ __launch_bounds__(256) void pack2_k(Pack2Args a){
  int seg = blockIdx.x >> 5;
  const float* s=a.src[seg]; uint32* d=a.dst[seg];
  int N=a.N[seg], K=a.K[seg], tot=N*(K>>1);
  for (int i=(blockIdx.x&31)*256+threadIdx.x; i<tot; i+=32*256){
    int k2=i/N, j=i-k2*N;
    float2 w = *(const float2*)(s + (size_t)j*K + 2*k2);
    d[(size_t)k2*N + j] = pk_f16(w.x, w.y);
  }
}

// ---------- pack Whh (enc+dec) f16 k-pairs, columns PERMUTED for in-wave gate exchange ----------
// dest column jc holds source gate-row jsrc = gate(jc)*128 + cell(jc),
// where gate(jc) = (jc>>4)&3, cell(jc) = (jc&15) + 16*(jc>>6)  (bijective).
__global__ __launch_bounds__(256) void pack_whh_k(
  const float* __restrict__ eWhh, const float* __restrict__ dWhh,
  uint32* __restrict__ wpkE, uint32* __restrict__ wpkD)
{
  int idx = blockIdx.x*256 + threadIdx.x;      // 131072 total
  int phase = idx >> 16;
  int rem = idx & 65535;
  int d = rem >> 15;
  int k2 = (rem >> 9) & 63;
  int jc = rem & 511;
  int gate = (jc>>4)&3;
  int cell = (jc&15) + 16*(jc>>6);
  int jsrc = gate*128 + cell;
  const float* Wsrc = phase ? dWhh : eWhh;
  float2 wa = *(const float2*)(Wsrc + ((size_t)(d*512 + jsrc))*128 + 2*k2);
  (phase ? wpkD : wpkE)[rem] = pk_f16(wa.x, wa.y);
}

// ---------- xg = x @ Wih^T + b via f16 dot2, flat f16 [d][b][t][512]. shift=1 for decoder ----------
__global__ __launch_bounds__(256) void xg_k(
  const float* __restrict__ x, const uint32* __restrict__ wx, const float* __restrict__ bias,
  __half* __restrict__ xgh, int shift)
{
  int d = blockIdx.x >> 11;
  int blk = blockIdx.x & 2047;
  int b = blk >> 3, t0 = (blk & 7) * 16;
  int tid = threadIdx.x;
  __shared__ __align__(16) uint32 xs[16][40];   // 38 used, rows padded to 160B
  for (int i=tid;i<16*38;i+=256){
    int r=i/38, k2=i-r*38, ts=t0+r-shift;
    float2 xv = (ts>=0) ? *(const float2*)(x + ((size_t)b*T+ts)*D + 2*k2) : make_float2(0.f,0.f);
    xs[r][k2] = pk_f16(xv.x, xv.y);
  }
  __syncthreads();
  const uint32* W = wx + (size_t)d*38*512;
  float a0[16], a1[16];
  #pragma unroll
  for(int r=0;r<16;r++){a0[r]=0.f;a1[r]=0.f;}
  #pragma unroll
  for (int k8=0;k8<9;k8++){
    int k2=4*k8;
    uint32 w00=W[(size_t)(k2+0)*512+tid], w01=W[(size_t)(k2+0)*512+tid+256];
    uint32 w10=W[(size_t)(k2+1)*512+tid], w11=W[(size_t)(k2+1)*512+tid+256];
    uint32 w20=W[(size_t)(k2+2)*512+tid], w21=W[(size_t)(k2+2)*512+tid+256];
    uint32 w30=W[(size_t)(k2+3)*512+tid], w31=W[(size_t)(k2+3)*512+tid+256];
    #pragma unroll
    for(int r=0;r<16;r++){
      uint4 u = *(const uint4*)&xs[r][k2];
      a0[r]=dot2(u.x,w00,a0[r]); a0[r]=dot2(u.y,w10,a0[r]);
      a0[r]=dot2(u.z,w20,a0[r]); a0[r]=dot2(u.w,w30,a0[r]);
      a1[r]=dot2(u.x,w01,a1[r]); a1[r]=dot2(u.y,w11,a1[r]);
      a1[r]=dot2(u.z,w21,a1[r]); a1[r]=dot2(u.w,w31,a1[r]);
    }
  }
  { // tail: k2 = 36, 37
    uint32 w00=W[(size_t)36*512+tid], w01=W[(size_t)36*512+tid+256];
    uint32 w10=W[(size_t)37*512+tid], w11=W[(size_t)37*512+tid+256];
    #pragma unroll
    for(int r=0;r<16;r++){
      uint2 u = *(const uint2*)&xs[r][36];
      a0[r]=dot2(u.x,w00,a0[r]); a0[r]=dot2(u.y,w10,a0[r]);
      a1[r]=dot2(u.x,w01,a1[r]); a1[r]=dot2(u.y,w11,a1[r]);
    }
  }
  float bb0=bias[d*G+tid], bb1=bias[d*G+tid+256];
  #pragma unroll
  for(int r=0;r<16;r++){
    size_t row = (size_t)(d*B + b)*T + (t0+r);
    xgh[row*512 + tid]       = __float2half(a0[r]+bb0);
    xgh[row*512 + tid + 256] = __float2half(a1[r]+bb1);
  }
}

// ---------- recurrence: in-wave gate exchange; 1 barrier/iter; hsd double-buffered ----------
// thread lane L holds gate (L>>4) of cell (L&15)+16*(tid>>6); source column jmap = gate*128+cell
// (wpk columns pre-permuted to match). Activation uniform: tanh(x)=2*sigm(2x)-1.
template<int ENC>
__global__ __launch_bounds__(512,2) void rec_k(
  const __half* __restrict__ xgh, const uint32* __restrict__ wpk,
  const __half* __restrict__ h16r, __half* __restrict__ on16,
  float* __restrict__ h_fin, uint32* __restrict__ h16w)
{
  int d = blockIdx.x >> 8;
  int b = blockIdx.x & 255;
  int tid = threadIdx.x;
  int lane = tid & 63;
  int gate = lane >> 4;                      // 0..3 (i,f,g,o)
  int cell = (lane & 15) + 16*(tid >> 6);    // 0..127
  int jmap = gate*128 + cell;
  __shared__ __align__(16) __half hsd[2][H];
  uint32 wreg[64];
  const uint32* wp = wpk + (size_t)d*64*512;
  #pragma unroll
  for (int k2=0;k2<64;k2++) wreg[k2] = wp[k2*512 + tid];
  if (tid < H){
    if (ENC) hsd[0][tid] = __float2half(0.f);
    else     hsd[0][tid] = h16r[((size_t)d*B + b)*H + tid];   // h16[t=0]
  }
  float creg = 0.f, hlast = 0.f;
  const __half* xrow = xgh + (size_t)(d*B + b)*T*512;
  int te0 = ENC ? (d ? (T-1) : 0) : 0;
  __half xr_next = xrow[(size_t)te0*512 + jmap];
  __syncthreads();
  int p = 0;
  for (int t=0;t<T;t++){
    int te = ENC ? (d ? (T-1-t) : t) : t;
    __half xr = xr_next;
    if (t+1 < T){
      int tn = ENC ? (d ? (T-2-t) : (t+1)) : (t+1);
      xr_next = xrow[(size_t)tn*512 + jmap];
    }
    const uint4* h128 = (const uint4*)hsd[p];
    float acc0 = 0.f, acc1 = 0.f;
    #pragma unroll
    for (int k8=0;k8<16;k8++){
      uint4 hv4 = h128[k8];
      acc0 = dot2(wreg[4*k8+0], hv4.x, acc0);
      acc1 = dot2(wreg[4*k8+1], hv4.y, acc1);
      acc0 = dot2(wreg[4*k8+2], hv4.z, acc0);
      acc1 = dot2(wreg[4*k8+3], hv4.w, acc1);
    }
    float gpre = acc0 + acc1 + __half2float(xr);
    // uniform activation: gates i,f,o -> sigm(x); gate g (==2) -> tanh(x)=2*sigm(2x)-1
    float kmul = (gate==2) ? 2.f : 1.f;
    float s = sigm(kmul*gpre);
    float act = (gate==2) ? fmaf(2.f, s, -1.f) : s;
    // in-wave gather to the cell (gate-0) lane
    int src = lane & 15;
    float f_ = __shfl(act, src+16, 64);
    float g_ = __shfl(act, src+32, 64);
    float o_ = __shfl(act, src+48, 64);
    if (gate==0){
      creg = f_*creg + act*g_;
      float hv = o_*fast_tanh(creg);
      hlast = hv;
      hsd[p^1][cell] = __float2half(hv);
      if (ENC){
        on16[((size_t)b*T + te)*H2 + d*H + cell] = __float2half(hv);
      } else {
        float nb = __shfl_xor(hv, 1);        // lanes 0..15 active; pairs adjacent cells
        if ((cell&1)==0)
          h16w[(((size_t)(t+1)*2 + d)*B + b)*64 + (cell>>1)] = pk_f16(hv, nb);
      }
    }
    __syncthreads();     // hsd[p^1] visible; hsd[p] free for overwrite next iter
    p ^= 1;
  }
  if (ENC && gate==0) h_fin[(size_t)d*B*H + (size_t)b*H + cell] = hlast;
}

// ---------- z = mu + eps*exp(0.5 lv) -> h16[0] (f16 pairs) ----------
__global__ __launch_bounds__(128) void z_k(
  const float* __restrict__ h_fin, const float* __restrict__ WzmuT, const float* __restrict__ bzmu,
  const float* __restrict__ WzlvT, const float* __restrict__ bzlv, const float* __restrict__ eps_z,
  uint32* __restrict__ h16w)
{
  __shared__ float hr[H];
  int d = blockIdx.x >> 8; int b = blockIdx.x & 255;
  int j = threadIdx.x;
  hr[j] = h_fin[(size_t)d*B*H + (size_t)b*H + j];
  __syncthreads();
  float mu=bzmu[j], lv=bzlv[j];
  #pragma unroll 4
  for(int k=0;k<H;k++){ float hv=hr[k]; mu+=hv*WzmuT[k*H+j]; lv+=hv*WzlvT[k*H+j]; }
  float z = mu + eps_z[(size_t)d*B*H + (size_t)b*H + j]*__expf(0.5f*lv);
  float nb = __shfl_xor(z, 1);
  if ((j&1)==0)
    h16w[(((size_t)0*2 + d)*B + b)*64 + (j>>1)] = pk_f16(z, nb);
}

// ---------- fused on_s (f16 dot2 GEMMs, b128 LDS): onsT + eb ----------
__global__ __launch_bounds__(256) void onsw2v_k(
  const uint32* __restrict__ on32, const uint32* __restrict__ wpmu, const float* __restrict__ bomu,
  const uint32* __restrict__ wplv, const float* __restrict__ bolv, const float* __restrict__ eps_on,
  const uint32* __restrict__ wp2, const float* __restrict__ b2,
  uint32* __restrict__ onsT, float* __restrict__ ebg)
{
  __shared__ __align__(16) uint32 tl[16][128];     // on (f16 pairs along k)
  __shared__ __align__(16) uint32 t2p[16][128];    // on_s (f16 pairs along j)
  size_t row0=(size_t)blockIdx.x*16;
  int b = (int)(row0 >> 7), t0 = (int)(row0 & 127);
  int tid=threadIdx.x;
  for(int i=tid;i<16*128;i+=256) ((uint32*)tl)[i] = on32[row0*128 + i];
  __syncthreads();
  float am[16], al[16];
  #pragma unroll
  for(int r=0;r<16;r++){am[r]=0.f;al[r]=0.f;}
  for(int k8=0;k8<32;k8++){
    int k2=4*k8;
    uint32 wm0=wpmu[(size_t)(k2+0)*H2+tid], wm1=wpmu[(size_t)(k2+1)*H2+tid];
    uint32 wm2=wpmu[(size_t)(k2+2)*H2+tid], wm3=wpmu[(size_t)(k2+3)*H2+tid];
    uint32 wl0=wplv[(size_t)(k2+0)*H2+tid], wl1=wplv[(size_t)(k2+1)*H2+tid];
    uint32 wl2=wplv[(size_t)(k2+2)*H2+tid], wl3=wplv[(size_t)(k2+3)*H2+tid];
    #pragma unroll
    for(int r=0;r<16;r++){
      uint4 u = *(const uint4*)&tl[r][k2];
      am[r]=dot2(u.x,wm0,am[r]); am[r]=dot2(u.y,wm1,am[r]);
      am[r]=dot2(u.z,wm2,am[r]); am[r]=dot2(u.w,wm3,am[r]);
      al[r]=dot2(u.x,wl0,al[r]); al[r]=dot2(u.y,wl1,al[r]);
      al[r]=dot2(u.z,wl2,al[r]); al[r]=dot2(u.w,wl3,al[r]);
    }
  }
  float bm=bomu[tid], bl=bolv[tid];
  float vv[16];
  #pragma unroll
  for(int r=0;r<16;r++){
    size_t row=row0+r;
    vv[r] = am[r]+bm + eps_on[row*H2+tid]*__expf(0.5f*(al[r]+bl));
  }
  // pack on_s pairs along j via shfl (even lanes write)
  #pragma unroll
  for(int r=0;r<16;r++){
    float nb = __shfl_xor(vv[r], 1);
    if ((tid&1)==0) t2p[r][tid>>1] = pk_f16(vv[r], nb);
  }
  __syncthreads();
  // on_s^T f16 t-pairs for PV: onsT[(b*256 + j)*64 + t/2]
  #pragma unroll
  for(int rr=0;rr<8;rr++){
    uint32 ua = t2p[2*rr][tid>>1], ub = t2p[2*rr+1][tid>>1];
    uint32 ha = (tid&1) ? (ua>>16) : (ua & 0xffffu);
    uint32 hb = (tid&1) ? (ub>>16) : (ub & 0xffffu);
    onsT[((size_t)b*H2 + tid)*64 + (t0>>1) + rr] = ha | (hb<<16);
  }
  // eb = exp(2*(on_s @ W2^T + b2))
  float ac[16];
  #pragma unroll
  for(int r=0;r<16;r++) ac[r]=0.f;
  for(int k8=0;k8<32;k8++){
    int k2=4*k8;
    uint32 w0=wp2[(size_t)(k2+0)*H2+tid], w1=wp2[(size_t)(k2+1)*H2+tid];
    uint32 w2=wp2[(size_t)(k2+2)*H2+tid], w3=wp2[(size_t)(k2+3)*H2+tid];
    #pragma unroll
    for(int r=0;r<16;r++){
      uint4 u = *(const uint4*)&t2p[r][k2];
      ac[r]=dot2(u.x,w0,ac[r]); ac[r]=dot2(u.y,w1,ac[r]);
      ac[r]=dot2(u.z,w2,ac[r]); ac[r]=dot2(u.w,w3,ac[r]);
    }
  }
  float bb=b2[tid];
  #pragma unroll
  for(int r=0;r<16;r++) ebg[(row0+r)*H2+tid]=__expf(2.0f*(ac[r]+bb));
}

// ---------- eq = exp(2*(concat(h0,h1)@W1T+b1)) via f16 dot2, b128 LDS ----------
__global__ __launch_bounds__(256) void qp_all_k(
  const uint32* __restrict__ h16, const uint32* __restrict__ wp1, const float* __restrict__ b1,
  float* __restrict__ eqg)
{
  int m0 = blockIdx.x*16; int b = m0>>7; int t0 = m0&127;
  __shared__ __align__(16) uint32 tile[16][128];
  int tid=threadIdx.x;
  for (int i=tid;i<16*128;i+=256){
    int r=i>>7, c=i&127; int dd=c>>6, kk2=c&63;
    tile[r][c] = h16[(((size_t)(t0+r)*2 + dd)*B + b)*64 + kk2];
  }
  __syncthreads();
  float ac[16];
  #pragma unroll
  for(int r=0;r<16;r++) ac[r]=0.f;
  for(int k8=0;k8<32;k8++){
    int k2=4*k8;
    uint32 w0=wp1[(size_t)(k2+0)*H2+tid], w1=wp1[(size_t)(k2+1)*H2+tid];
    uint32 w2=wp1[(size_t)(k2+2)*H2+tid], w3=wp1[(size_t)(k2+3)*H2+tid];
    #pragma unroll
    for(int r=0;r<16;r++){
      uint4 u = *(const uint4*)&tile[r][k2];
      ac[r]=dot2(u.x,w0,ac[r]); ac[r]=dot2(u.y,w1,ac[r]);
      ac[r]=dot2(u.z,w2,ac[r]); ac[r]=dot2(u.w,w3,ac[r]);
    }
  }
  float bb=b1[tid];
  #pragma unroll
  for(int r=0;r<16;r++) eqg[(size_t)(m0+r)*H2+tid]=__expf(2.0f*(ac[r]+bb));
}

// ---------- scores: grid (b, t-quarter of 32); TQ=2; padded 20-dword jq-blocks (bank-clean b128) ----------
__global__ __launch_bounds__(512,4) void score_k(
  const float* __restrict__ eqg, const float* __restrict__ ebg,
  const float* __restrict__ att_v, uint32* __restrict__ sc16)
{
  int b  = blockIdx.x >> 2;
  int t0 = (blockIdx.x & 3) * 32;
  int tid = threadIdx.x;
  int jq = tid & 15, ttb = tid >> 4;
  __shared__ __align__(16) float eqs[2][2*320];   // [buf][q*320 + jq*20 + ii]
  __shared__ __align__(16) float scl[2][2][T];
  __shared__ float wsum4[2][4];
  __shared__ __align__(16) float wvsp[320];       // padded -2*att_v
  uint32 ebp01[16], ebp23[16];
  float vsum_mine = 0.f;
  {
    const float* ebb = ebg + (size_t)b*T*H2;
    #pragma unroll
    for (int ii=0;ii<16;ii++){
      int j = 16*jq + ii;
      ebp01[ii] = pk_bf16(ebb[(size_t)(ttb    )*H2 + j], ebb[(size_t)(ttb+32)*H2 + j]);
      ebp23[ii] = pk_bf16(ebb[(size_t)(ttb+64 )*H2 + j], ebb[(size_t)(ttb+96)*H2 + j]);
      vsum_mine += att_v[j];
    }
  }
  if (tid < H2) wvsp[(tid>>4)*20 + (tid&15)] = -2.0f*att_v[tid];
  if (tid < 128){
    float4 v = ((const float4*)(eqg + ((size_t)b*T + t0)*H2))[tid];
    int l=4*tid, q=l>>8, jj=l&255;
    *(float4*)&eqs[0][q*320 + (jj>>4)*20 + (jj&15)] = v;
  }
  __syncthreads();
  int buf = 0;
  for (int tq=0; tq<32; tq+=2){
    int cur = (tq>>1)&1;
    if (tq+2 < 32 && tid < 128){
      float4 v = ((const float4*)(eqg + ((size_t)b*T + t0+tq+2)*H2))[tid];
      int l=4*tid, q=l>>8, jj=l&255;
      *(float4*)&eqs[buf^1][q*320 + (jj>>4)*20 + (jj&15)] = v;
    }
    const float* eq0 = eqs[buf];
    const float* eq1 = eqs[buf] + 320;
    float a00=vsum_mine,a01=vsum_mine,a02=vsum_mine,a03=vsum_mine;
    float a10=vsum_mine,a11=vsum_mine,a12=vsum_mine,a13=vsum_mine;
    #pragma unroll
    for (int ii4=0; ii4<4; ii4++){
      float4 q0 = *(const float4*)&eq0[jq*20 + 4*ii4];
      float4 q1 = *(const float4*)&eq1[jq*20 + 4*ii4];
      float4 w4 = *(const float4*)&wvsp[jq*20 + 4*ii4];
      #pragma unroll
      for (int c=0;c<4;c++){
        int ii = 4*ii4 + c;
        float e0=bflo(ebp01[ii]), e1=bfhi(ebp01[ii]);
        float e2=bflo(ebp23[ii]), e3=bfhi(ebp23[ii]);
        float q0c = (c==0)?q0.x:(c==1)?q0.y:(c==2)?q0.z:q0.w;
        float q1c = (c==0)?q1.x:(c==1)?q1.y:(c==2)?q1.z:q1.w;
        float w   = (c==0)?w4.x:(c==1)?w4.y:(c==2)?w4.z:w4.w;
        a00 = fmaf(w, fast_rcp(fmaf(e0,q0c,1.f)), a00);
        a01 = fmaf(w, fast_rcp(fmaf(e1,q0c,1.f)), a01);
        a02 = fmaf(w, fast_rcp(fmaf(e2,q0c,1.f)), a02);
        a03 = fmaf(w, fast_rcp(fmaf(e3,q0c,1.f)), a03);
        a10 = fmaf(w, fast_rcp(fmaf(e0,q1c,1.f)), a10);
        a11 = fmaf(w, fast_rcp(fmaf(e1,q1c,1.f)), a11);
        a12 = fmaf(w, fast_rcp(fmaf(e2,q1c,1.f)), a12);
        a13 = fmaf(w, fast_rcp(fmaf(e3,q1c,1.f)), a13);
      }
    }
    #pragma unroll
    for (int off=1; off<16; off<<=1){
      a00 += __shfl_xor(a00,off); a01 += __shfl_xor(a01,off);
      a02 += __shfl_xor(a02,off); a03 += __shfl_xor(a03,off);
      a10 += __shfl_xor(a10,off); a11 += __shfl_xor(a11,off);
      a12 += __shfl_xor(a12,off); a13 += __shfl_xor(a13,off);
    }
    if (jq==0){
      scl[cur][0][ttb]=__expf(a00); scl[cur][0][ttb+32]=__expf(a01);
      scl[cur][0][ttb+64]=__expf(a02); scl[cur][0][ttb+96]=__expf(a03);
      scl[cur][1][ttb]=__expf(a10); scl[cur][1][ttb+32]=__expf(a11);
      scl[cur][1][ttb+64]=__expf(a12); scl[cur][1][ttb+96]=__expf(a13);
    }
    __syncthreads();                          // A: scl[cur] ready
    if (tid < 256){
      int row = tid>>7;
      float e = scl[cur][row][tid&127];
      #pragma unroll
      for (int off=1; off<64; off<<=1) e += __shfl_xor(e,off);
      if ((tid&63)==0) wsum4[cur][tid>>6]=e;
    }
    __syncthreads();                          // B: wsum ready
    if (tid < 128){
      int row = tid>>6, i = tid&63;
      float tot = wsum4[cur][row*2] + wsum4[cur][row*2+1];
      float inv = fast_rcp(tot*128.0f);
      sc16[((size_t)b*T + t0+tq+row)*64 + i] =
        pk_f16(scl[cur][row][2*i]*inv, scl[cur][row][2*i+1]*inv);
    }
    buf ^= 1;
  }
}

// ---------- fused PV + output projection: ctx never leaves LDS ----------
__global__ __launch_bounds__(256,2) void pvout_k(
  const uint32* __restrict__ sc16, const uint32* __restrict__ onsT,
  const uint32* __restrict__ h16, const uint32* __restrict__ wpout,
  const float* __restrict__ bout, float* __restrict__ out)
{
  int b  = blockIdx.x >> 3;
  int t0 = (blockIdx.x & 7) * 16;
  int m0 = blockIdx.x*16;
  int tid = threadIdx.x;                 // PV: output column j
  __shared__ uint32 scs[16][64];                   // 4 KB
  __shared__ __align__(16) uint32 rb[16][256];     // 16 KB: [h0|h1|ctx] f16 pairs
  uint4 vreg[16];
  {
    const uint4* vp = (const uint4*)(onsT + ((size_t)b*H2 + tid)*64);
    #pragma unroll
    for (int k=0;k<16;k++) vreg[k] = vp[k];
  }
  for (int i=tid;i<1024;i+=256) ((uint32*)scs)[i] = sc16[((size_t)b*T + t0)*64 + i];
  for (int i=tid;i<16*128;i+=256){
    int r=i>>7, c=i&127;
    int t = t0+r;
    rb[r][c] = (c<64) ? h16[(((size_t)(t+1)*2 + 0)*B + b)*64 + c]
                      : h16[(((size_t)(t+1)*2 + 1)*B + b)*64 + (c-64)];
  }
  __syncthreads();
  // phase A: PV -> ctx into rb[.][128..255]
  for (int qt=0; qt<16; qt++){
    float a0=0.f,a1=0.f,a2=0.f,a3=0.f;
    #pragma unroll
    for (int k=0;k<16;k++){
      a0 = dot2(scs[qt][4*k+0], vreg[k].x, a0);
      a1 = dot2(scs[qt][4*k+1], vreg[k].y, a1);
      a2 = dot2(scs[qt][4*k+2], vreg[k].z, a2);
      a3 = dot2(scs[qt][4*k+3], vreg[k].w, a3);
    }
    float mine = (a0+a1)+(a2+a3);
    float nb = __shfl_xor(mine, 1);
    if ((tid&1)==0) rb[qt][128 + (tid>>1)] = pk_f16(mine, nb);
  }
  __syncthreads();
  // phase B: out = rb @ Wout^T + bout
  for (int o=tid;o<16*D;o+=256){
    int r=o/D, j=o-r*D;
    float acc=bout[j];
    for (int k4=0;k4<64;k4++){
      uint4 u = *(const uint4*)&rb[r][4*k4];
      acc = dot2(u.x, wpout[(size_t)(4*k4+0)*D+j], acc);
      acc = dot2(u.y, wpout[(size_t)(4*k4+1)*D+j], acc);
      acc = dot2(u.z, wpout[(size_t)(4*k4+2)*D+j], acc);
      acc = dot2(u.w, wpout[(size_t)(4*k4+3)*D+j], acc);
    }
    out[((size_t)(m0+r))*D + j]=acc;
  }
}

extern "C" void kernel_launch(void* const* d_in, const int* in_sizes, int n_in,
                              void* d_out, int out_size, void* d_ws, size_t ws_size,
                              hipStream_t stream) {
  const float* x      =(const float*)d_in[0];
  const float* eps_z  =(const float*)d_in[1];
  const float* eps_on =(const float*)d_in[2];
  const float* enc_Wih=(const float*)d_in[3];
  const float* enc_Whh=(const float*)d_in[4];
  const float* enc_b  =(const float*)d_in[5];
  const float* dec_Wih=(const float*)d_in[6];
  const float* dec_Whh=(const float*)d_in[7];
  const float* dec_b  =(const float*)d_in[8];
  const float* Wzmu=(const float*)d_in[9];  const float* bzmu=(const float*)d_in[10];
  const float* Wzlv=(const float*)d_in[11]; const float* bzlv=(const float*)d_in[12];
  const float* Womu=(const float*)d_in[13]; const float* bomu=(const float*)d_in[14];
  const float* Wolv=(const float*)d_in[15]; const float* bolv=(const float*)d_in[16];
  const float* att_v=(const float*)d_in[17];
  const float* att_W1=(const float*)d_in[18]; const float* att_b1=(const float*)d_in[19];
  const float* att_W2=(const float*)d_in[20]; const float* att_b2=(const float*)d_in[21];
  const float* Wout=(const float*)d_in[22];  const float* bout=(const float*)d_in[23];
  float* out=(float*)d_out;
  float* ws=(float*)d_ws;
  (void)ws_size; (void)n_in; (void)in_sizes; (void)out_size;

  size_t o=0;
  float* WzmuT=ws+o; o+=H*H;
  float* WzlvT=ws+o; o+=H*H;
  uint32* wpkE=(uint32*)(ws+o); o+=65536;
  uint32* wpkD=(uint32*)(ws+o); o+=65536;
  uint32* wpmu=(uint32*)(ws+o); o+=32768;   // [k2=128][256]
  uint32* wplv=(uint32*)(ws+o); o+=32768;
  uint32* wp1 =(uint32*)(ws+o); o+=32768;
  uint32* wp2 =(uint32*)(ws+o); o+=32768;
  uint32* wpout=(uint32*)(ws+o); o+=19456;  // [k2=256][76]
  uint32* wxE =(uint32*)(ws+o); o+=38912;   // [d][k2=38][512]
  uint32* wxD =(uint32*)(ws+o); o+=38912;
  float* h_fin=ws+o; o+=2*B*H;
  __half* on16=(__half*)(ws+o); o+=(size_t)B*T*H2/2;
  uint32* h16 =(uint32*)(ws+o); o+=(size_t)(T+1)*2*B*64;   // f16 pairs [t][d][b][h/2]
  float* Abase=ws+o; o+=16777216;                // 64MB: xgh (full) -> eqg (lower half)
  float* Cbase=ws+o; o+=14680064;                // 56MB: onsT 16MB + ebg 32MB + sc16 8MB

  __half* xgh = (__half*)Abase;                  // 64MB: [d][b][t][512] f16, reused enc->dec
  float* eqg  = Abase;
  uint32* onsT = (uint32*)Cbase;
  float* ebg  = Cbase + 4194304;
  uint32* sc16 = (uint32*)(Cbase + 4194304 + 8388608);

  PrepArgs pa;
  {
    const float* srcs[2]={Wzmu,Wzlv};
    float* dsts[2]={WzmuT,WzlvT};
    for(int i=0;i<2;i++){pa.src[i]=srcs[i];pa.dst[i]=dsts[i];pa.R[i]=H;pa.C[i]=H;}
  }
  Pack2Args p2;
  {
    const float* srcs[9]={Womu,Wolv,att_W1,att_W2,Wout,
                          enc_Wih, enc_Wih + (size_t)512*76,
                          dec_Wih, dec_Wih + (size_t)512*76};
    uint32* dsts[9]={wpmu,wplv,wp1,wp2,wpout, wxE, wxE+19456, wxD, wxD+19456};
    int Ns[9]={H2,H2,H2,H2,D, 512,512,512,512};
    int Ks[9]={H2,H2,H2,H2,G, D,D,D,D};
    for(int i=0;i<9;i++){p2.src[i]=srcs[i];p2.dst[i]=dsts[i];p2.N[i]=Ns[i];p2.K[i]=Ks[i];}
  }
  prep_k<<<64,256,0,stream>>>(pa);
  pack2_k<<<288,256,0,stream>>>(p2);
  pack_whh_k<<<512,256,0,stream>>>(enc_Whh, dec_Whh, wpkE, wpkD);

  // encoder phase (xgh occupies all of Abase; consumed by rec before reuse)
  xg_k<<<4096,256,0,stream>>>(x, wxE, enc_b, xgh, 0);
  rec_k<1><<<512,512,0,stream>>>(xgh, wpkE, nullptr, on16, h_fin, nullptr);
  z_k<<<512,128,0,stream>>>(h_fin, WzmuT,bzmu,WzlvT,bzlv,eps_z, h16);
  onsw2v_k<<<2048,256,0,stream>>>((const uint32*)on16,wpmu,bomu,wplv,bolv,eps_on,wp2,att_b2,onsT,ebg);

  // decoder phase (xgh rewritten for dec; then eqg overwrites lower half after rec_k<0>)
  xg_k<<<4096,256,0,stream>>>(x, wxD, dec_b, xgh, 1);
  rec_k<0><<<512,512,0,stream>>>(xgh, wpkD, (const __half*)h16, nullptr, nullptr, h16);

  qp_all_k<<<2048,256,0,stream>>>(h16, wp1, att_b1, eqg);
  score_k<<<1024,512,0,stream>>>(eqg, ebg, att_v, sc16);
  pvout_k<<<2048,256,0,stream>>>(sc16, onsT, h16, wpout, bout, out);
}